// Round 1
// baseline (1567.204 us; speedup 1.0000x reference)
//
#include <hip/hip_runtime.h>
#include <cstddef>

// Problem constants (B=16, S=1024, D=256, H=8 -> H2=4 heads/branch, DEPTH=32, DH=128)
static constexpr int BB = 16, SS = 1024, DD = 256;
static constexpr size_t OUTW = (size_t)BB * SS * DD;          // 4,194,304 floats: start of attn_w in d_out
#define SCALE 0.17677669529663687f                             // 1/sqrt(32)

// ---------------------------------------------------------------------------
// pack: Wcat[g] = [W_dist | W_adj] (256x256) for g in {q,k,v}; bcat likewise
// ---------------------------------------------------------------------------
__global__ __launch_bounds__(256) void pack_kernel(
    const float* __restrict__ Wqd, const float* __restrict__ Wqa,
    const float* __restrict__ Wkd, const float* __restrict__ Wka,
    const float* __restrict__ Wvd, const float* __restrict__ Wva,
    const float* __restrict__ bqd, const float* __restrict__ bqa,
    const float* __restrict__ bkd, const float* __restrict__ bka,
    const float* __restrict__ bvd, const float* __restrict__ bva,
    float* __restrict__ Wcat, float* __restrict__ bcat)
{
  int i = blockIdx.x * 256 + threadIdx.x;
  if (i < 3 * 256 * 256) {
    int g = i >> 16, r = (i >> 8) & 255, n = i & 255;
    const float* W0 = (g == 0) ? Wqd : (g == 1) ? Wkd : Wvd;
    const float* W1 = (g == 0) ? Wqa : (g == 1) ? Wka : Wva;
    Wcat[i] = (n < 128) ? W0[r * 128 + n] : W1[r * 128 + (n - 128)];
  } else {
    int j = i - 3 * 256 * 256;
    if (j < 3 * 256) {
      int g = j >> 8, n = j & 255;
      const float* b0 = (g == 0) ? bqd : (g == 1) ? bkd : bvd;
      const float* b1 = (g == 0) ? bqa : (g == 1) ? bka : bva;
      bcat[j] = (n < 128) ? b0[n] : b1[n - 128];
    }
  }
}

// ---------------------------------------------------------------------------
// gemm256: Y[M x 256] = X[M x 256] @ W[256 x 256] + bias. 64x64 block tile,
// 4x4 micro-tile per thread, 16-wide K chunks staged in LDS.
// ---------------------------------------------------------------------------
__global__ __launch_bounds__(256) void gemm256_kernel(
    const float* __restrict__ X, const float* __restrict__ W,
    const float* __restrict__ bias, float* __restrict__ Y)
{
  __shared__ float As[16][68];   // [k][m], pad 68 keeps b128 alignment + bank spread
  __shared__ float Bs[16][68];   // [k][n]
  const int t = threadIdx.x;
  const int m0 = blockIdx.x * 64;
  const int n0 = blockIdx.y * 64;
  const int tm = t >> 4, tn = t & 15;
  const int mA = t >> 2, kqA = t & 3;   // A staging: row mA, k-quad kqA
  const int kB = t >> 4, nqB = t & 15;  // B staging: k row kB, n-quad nqB

  float acc[4][4];
#pragma unroll
  for (int i = 0; i < 4; ++i)
#pragma unroll
    for (int j = 0; j < 4; ++j) acc[i][j] = 0.f;

  for (int k0 = 0; k0 < 256; k0 += 16) {
    float4 a = *(const float4*)&X[(size_t)(m0 + mA) * 256 + k0 + 4 * kqA];
    float4 b = *(const float4*)&W[(size_t)(k0 + kB) * 256 + n0 + 4 * nqB];
    __syncthreads();
    As[4 * kqA + 0][mA] = a.x;
    As[4 * kqA + 1][mA] = a.y;
    As[4 * kqA + 2][mA] = a.z;
    As[4 * kqA + 3][mA] = a.w;
    *(float4*)&Bs[kB][4 * nqB] = b;
    __syncthreads();
#pragma unroll
    for (int kk = 0; kk < 16; ++kk) {
      float4 av = *(const float4*)&As[kk][4 * tm];
      float4 bv = *(const float4*)&Bs[kk][4 * tn];
      float ar[4] = {av.x, av.y, av.z, av.w};
      float br[4] = {bv.x, bv.y, bv.z, bv.w};
#pragma unroll
      for (int i = 0; i < 4; ++i)
#pragma unroll
        for (int j = 0; j < 4; ++j) acc[i][j] = fmaf(ar[i], br[j], acc[i][j]);
    }
  }
  float4 bv = *(const float4*)&bias[n0 + 4 * tn];
#pragma unroll
  for (int i = 0; i < 4; ++i) {
    float4 o;
    o.x = acc[i][0] + bv.x; o.y = acc[i][1] + bv.y;
    o.z = acc[i][2] + bv.z; o.w = acc[i][3] + bv.w;
    *(float4*)&Y[(size_t)(m0 + 4 * tm + i) * 256 + n0 + 4 * tn] = o;
  }
}

// ---------------------------------------------------------------------------
// dist_stats: per (b,q) row of dist+neg -> rowmax and 1/sum(exp)
// one wave per row, 4 rows per block
// ---------------------------------------------------------------------------
__global__ __launch_bounds__(256) void dist_stats_kernel(
    const float* __restrict__ dist, const float* __restrict__ mask,
    float* __restrict__ dmax, float* __restrict__ dinv)
{
  const int t = threadIdx.x;
  const int w = t >> 6, lane = t & 63;
  const int row = blockIdx.x * 4 + w;        // b*S + q
  const int b = row >> 10;
  const float* dr = dist + (size_t)row * 1024;
  const float* mr = mask + b * 1024;
  float v[16];
  float m = -3.0e38f;
#pragma unroll
  for (int j = 0; j < 16; ++j) {
    int c = lane + 64 * j;
    v[j] = dr[c] - 1e9f * mr[c];
    m = fmaxf(m, v[j]);
  }
#pragma unroll
  for (int off = 32; off >= 1; off >>= 1) m = fmaxf(m, __shfl_xor(m, off));
  float s = 0.f;
#pragma unroll
  for (int j = 0; j < 16; ++j) s += __expf(v[j] - m);
#pragma unroll
  for (int off = 32; off >= 1; off >>= 1) s += __shfl_xor(s, off);
  if (lane == 0) { dmax[row] = m; dinv[row] = 1.0f / s; }
}

// ---------------------------------------------------------------------------
// attn_logits: per block = (b, h, 16 q-rows). Computes logits (QK^T*scale+neg),
// row softmax, multiplies by adj (h>=4) or softmax(dist+neg) (h<4), writes w.
// Thread layout: tp = t>>5 (row-pair), tc = t&31 (cols tc+32j, j=0..31).
// ---------------------------------------------------------------------------
__global__ __launch_bounds__(256) void attn_logits_kernel(
    const float* __restrict__ Qc, const float* __restrict__ Kc,
    const float* __restrict__ mask, const float* __restrict__ adj,
    const float* __restrict__ dist, const float* __restrict__ dmax,
    const float* __restrict__ dinv, float* __restrict__ wout)
{
  __shared__ float Ks[64][36];    // 64 k-cols x 32 dims, pad 36 (b128-aligned)
  const int t = threadIdx.x;
  const int bid = blockIdx.x;
  const int qb = bid & 63;
  const int h = (bid >> 6) & 7;
  const int b = bid >> 9;
  const int q0 = qb * 16;
  const int branch = h >> 2;
  const int boff = branch * 128 + (h & 3) * 32;
  const int tp = t >> 5, tc = t & 31;
  const int r0 = q0 + 2 * tp;                 // this thread's two rows: r0, r0+1

  // Q rows into registers
  const float* qrow0 = Qc + ((size_t)(b * 1024 + r0)) * 256 + boff;
  const float* qrow1 = qrow0 + 256;
  float Q0[32], Q1[32];
#pragma unroll
  for (int dq = 0; dq < 8; ++dq) {
    float4 a = *(const float4*)&qrow0[4 * dq];
    Q0[4 * dq + 0] = a.x; Q0[4 * dq + 1] = a.y; Q0[4 * dq + 2] = a.z; Q0[4 * dq + 3] = a.w;
    float4 c = *(const float4*)&qrow1[4 * dq];
    Q1[4 * dq + 0] = c.x; Q1[4 * dq + 1] = c.y; Q1[4 * dq + 2] = c.z; Q1[4 * dq + 3] = c.w;
  }

  float L0[32], L1[32];
  const float* kb0 = Kc + (size_t)(b * 1024) * 256 + boff;
  const int sr = t >> 2, sq = t & 3;          // staging: row sr (0..63), d-quads sq, sq+4

#pragma unroll
  for (int cc = 0; cc < 16; ++cc) {
    const int c0 = cc * 64;
    float4 ka = *(const float4*)&kb0[(size_t)(c0 + sr) * 256 + 4 * sq];
    float4 kc = *(const float4*)&kb0[(size_t)(c0 + sr) * 256 + 16 + 4 * sq];
    __syncthreads();
    *(float4*)&Ks[sr][4 * sq] = ka;
    *(float4*)&Ks[sr][16 + 4 * sq] = kc;
    __syncthreads();
#pragma unroll
    for (int j2 = 0; j2 < 2; ++j2) {
      const int cl = tc + 32 * j2;
      float s0 = 0.f, s1 = 0.f;
#pragma unroll
      for (int dq = 0; dq < 8; ++dq) {
        float4 kv = *(const float4*)&Ks[cl][4 * dq];
        s0 = fmaf(Q0[4 * dq + 0], kv.x, s0);
        s0 = fmaf(Q0[4 * dq + 1], kv.y, s0);
        s0 = fmaf(Q0[4 * dq + 2], kv.z, s0);
        s0 = fmaf(Q0[4 * dq + 3], kv.w, s0);
        s1 = fmaf(Q1[4 * dq + 0], kv.x, s1);
        s1 = fmaf(Q1[4 * dq + 1], kv.y, s1);
        s1 = fmaf(Q1[4 * dq + 2], kv.z, s1);
        s1 = fmaf(Q1[4 * dq + 3], kv.w, s1);
      }
      L0[cc * 2 + j2] = s0;
      L1[cc * 2 + j2] = s1;
    }
  }

  // scale + mask, row max
  const float* mr = mask + b * 1024;
  float m0v = -3.0e38f, m1v = -3.0e38f;
#pragma unroll
  for (int j = 0; j < 32; ++j) {
    float ng = -1e9f * mr[tc + 32 * j];
    L0[j] = L0[j] * SCALE + ng;
    L1[j] = L1[j] * SCALE + ng;
    m0v = fmaxf(m0v, L0[j]);
    m1v = fmaxf(m1v, L1[j]);
  }
#pragma unroll
  for (int off = 16; off >= 1; off >>= 1) {
    m0v = fmaxf(m0v, __shfl_xor(m0v, off));
    m1v = fmaxf(m1v, __shfl_xor(m1v, off));
  }
  // exp + row sum
  float s0v = 0.f, s1v = 0.f;
#pragma unroll
  for (int j = 0; j < 32; ++j) {
    L0[j] = __expf(L0[j] - m0v); s0v += L0[j];
    L1[j] = __expf(L1[j] - m1v); s1v += L1[j];
  }
#pragma unroll
  for (int off = 16; off >= 1; off >>= 1) {
    s0v += __shfl_xor(s0v, off);
    s1v += __shfl_xor(s1v, off);
  }
  const float r0i = 1.0f / s0v, r1i = 1.0f / s1v;

  // reweight + store w
  const size_t wrow0 = ((size_t)(b * 8 + h) * 1024 + r0) * 1024;
  const size_t wrow1 = wrow0 + 1024;
  if (branch == 0) {
    const float dm0 = dmax[b * 1024 + r0], di0 = dinv[b * 1024 + r0];
    const float dm1 = dmax[b * 1024 + r0 + 1], di1 = dinv[b * 1024 + r0 + 1];
    const float* dr0 = dist + (size_t)(b * 1024 + r0) * 1024;
    const float* dr1 = dr0 + 1024;
#pragma unroll 4
    for (int j = 0; j < 32; ++j) {
      int c = tc + 32 * j;
      float ng = -1e9f * mr[c];
      wout[wrow0 + c] = L0[j] * r0i * (__expf(dr0[c] + ng - dm0) * di0);
      wout[wrow1 + c] = L1[j] * r1i * (__expf(dr1[c] + ng - dm1) * di1);
    }
  } else {
    const float* ar0 = adj + (size_t)(b * 1024 + r0) * 1024;
    const float* ar1 = ar0 + 1024;
#pragma unroll 4
    for (int j = 0; j < 32; ++j) {
      int c = tc + 32 * j;
      wout[wrow0 + c] = L0[j] * r0i * ar0[c];
      wout[wrow1 + c] = L1[j] * r1i * ar1[c];
    }
  }
}

// ---------------------------------------------------------------------------
// attn_pv: o = w @ V per (b,h). Block = 128 q-rows; thread = 4 rows x 4 dims.
// Writes into concat layout (B,S,256): feature = branch*128 + h2*32 + d.
// ---------------------------------------------------------------------------
__global__ __launch_bounds__(256) void attn_pv_kernel(
    const float* __restrict__ wsrc, const float* __restrict__ Vc,
    float* __restrict__ conc)
{
  __shared__ float Ws[128][36];   // 128 rows x 32 k
  __shared__ float Vs[32][36];    // 32 k x 32 dims
  const int t = threadIdx.x;
  const int bid = blockIdx.x;                  // 1024 blocks
  const int qb = bid & 7;
  const int h = (bid >> 3) & 7;
  const int b = bid >> 6;
  const int q0 = qb * 128;
  const int branch = h >> 2;
  const int boff = branch * 128 + (h & 3) * 32;
  const float* wb = wsrc + ((size_t)(b * 8 + h) * 1024 + q0) * 1024;
  const float* vb = Vc + (size_t)(b * 1024) * 256 + boff;
  const int ty = t >> 3, td = t & 7;           // rows 4*ty..+3, dims 4*td..+3
  const int swr = t >> 3, swk = t & 7;         // Ws staging
  const int svk = t >> 3, svd = t & 7;         // Vs staging

  float acc[4][4];
#pragma unroll
  for (int i = 0; i < 4; ++i)
#pragma unroll
    for (int j = 0; j < 4; ++j) acc[i][j] = 0.f;

  for (int k0 = 0; k0 < 1024; k0 += 32) {
    float4 wv[4];
#pragma unroll
    for (int i = 0; i < 4; ++i)
      wv[i] = *(const float4*)&wb[(size_t)(swr + 32 * i) * 1024 + k0 + 4 * swk];
    float4 vv4 = *(const float4*)&vb[(size_t)(k0 + svk) * 256 + 4 * svd];
    __syncthreads();
#pragma unroll
    for (int i = 0; i < 4; ++i) *(float4*)&Ws[swr + 32 * i][4 * swk] = wv[i];
    *(float4*)&Vs[svk][4 * svd] = vv4;
    __syncthreads();
#pragma unroll
    for (int kq = 0; kq < 8; ++kq) {
      float vvv[4][4];
#pragma unroll
      for (int kk = 0; kk < 4; ++kk) {
        float4 tv = *(const float4*)&Vs[4 * kq + kk][4 * td];
        vvv[kk][0] = tv.x; vvv[kk][1] = tv.y; vvv[kk][2] = tv.z; vvv[kk][3] = tv.w;
      }
#pragma unroll
      for (int i = 0; i < 4; ++i) {
        float4 wq = *(const float4*)&Ws[4 * ty + i][4 * kq];
        float wr[4] = {wq.x, wq.y, wq.z, wq.w};
#pragma unroll
        for (int kk = 0; kk < 4; ++kk)
#pragma unroll
          for (int j = 0; j < 4; ++j)
            acc[i][j] = fmaf(wr[kk], vvv[kk][j], acc[i][j]);
      }
    }
  }
#pragma unroll
  for (int i = 0; i < 4; ++i) {
    int q = q0 + 4 * ty + i;
    float4 o;
    o.x = acc[i][0]; o.y = acc[i][1]; o.z = acc[i][2]; o.w = acc[i][3];
    *(float4*)&conc[((size_t)(b * 1024) + q) * 256 + boff + 4 * td] = o;
  }
}

// ---------------------------------------------------------------------------
extern "C" void kernel_launch(void* const* d_in, const int* in_sizes, int n_in,
                              void* d_out, int out_size, void* d_ws, size_t ws_size,
                              hipStream_t stream)
{
  const float* v_ori = (const float*)d_in[0];
  const float* k_ori = (const float*)d_in[1];
  const float* q_ori = (const float*)d_in[2];
  const float* mask  = (const float*)d_in[3];
  const float* adj   = (const float*)d_in[4];
  const float* dist  = (const float*)d_in[5];
  const float* Wqd = (const float*)d_in[6];  const float* bqd = (const float*)d_in[7];
  const float* Wkd = (const float*)d_in[8];  const float* bkd = (const float*)d_in[9];
  const float* Wvd = (const float*)d_in[10]; const float* bvd = (const float*)d_in[11];
  const float* Wqa = (const float*)d_in[12]; const float* bqa = (const float*)d_in[13];
  const float* Wka = (const float*)d_in[14]; const float* bka = (const float*)d_in[15];
  const float* Wva = (const float*)d_in[16]; const float* bva = (const float*)d_in[17];
  const float* Wo  = (const float*)d_in[18]; const float* bo  = (const float*)d_in[19];

  float* out = (float*)d_out;
  float* ws  = (float*)d_ws;
  float* Qc    = ws;                  // 16384*256
  float* Kc    = Qc + 4194304;
  float* Vc    = Kc + 4194304;
  float* conc  = Vc + 4194304;        // 16384*256
  float* dmaxb = conc + 4194304;      // 16384
  float* dinvb = dmaxb + 16384;       // 16384
  float* Wcat  = dinvb + 16384;       // 3*65536
  float* bcat  = Wcat + 196608;       // 3*256

  pack_kernel<<<771, 256, 0, stream>>>(Wqd, Wqa, Wkd, Wka, Wvd, Wva,
                                       bqd, bqa, bkd, bka, bvd, bva, Wcat, bcat);
  dim3 gg(256, 4);
  gemm256_kernel<<<gg, 256, 0, stream>>>(q_ori, Wcat,          bcat,       Qc);
  gemm256_kernel<<<gg, 256, 0, stream>>>(k_ori, Wcat + 65536,  bcat + 256, Kc);
  gemm256_kernel<<<gg, 256, 0, stream>>>(v_ori, Wcat + 131072, bcat + 512, Vc);
  dist_stats_kernel<<<4096, 256, 0, stream>>>(dist, mask, dmaxb, dinvb);
  attn_logits_kernel<<<8192, 256, 0, stream>>>(Qc, Kc, mask, adj, dist, dmaxb, dinvb,
                                               out + OUTW);
  attn_pv_kernel<<<1024, 256, 0, stream>>>(out + OUTW, Vc, conc);
  gemm256_kernel<<<gg, 256, 0, stream>>>(conc, Wo, bo, out);
}

// Round 2
// 1481.708 us; speedup vs baseline: 1.0577x; 1.0577x over previous
//
#include <hip/hip_runtime.h>
#include <cstddef>

// Problem constants (B=16, S=1024, D=256, H=8 -> H2=4 heads/branch, DEPTH=32, DH=128)
static constexpr int BB = 16, SS = 1024, DD = 256;
static constexpr size_t OUTW = (size_t)BB * SS * DD;          // 4,194,304 floats: start of attn_w in d_out
#define SCALE 0.17677669529663687f                             // 1/sqrt(32)

// ---------------------------------------------------------------------------
// pack: Wcat[g] = [W_dist | W_adj] (256x256) for g in {q,k,v}; bcat likewise
// ---------------------------------------------------------------------------
__global__ __launch_bounds__(256) void pack_kernel(
    const float* __restrict__ Wqd, const float* __restrict__ Wqa,
    const float* __restrict__ Wkd, const float* __restrict__ Wka,
    const float* __restrict__ Wvd, const float* __restrict__ Wva,
    const float* __restrict__ bqd, const float* __restrict__ bqa,
    const float* __restrict__ bkd, const float* __restrict__ bka,
    const float* __restrict__ bvd, const float* __restrict__ bva,
    float* __restrict__ Wcat, float* __restrict__ bcat)
{
  int i = blockIdx.x * 256 + threadIdx.x;
  if (i < 3 * 256 * 256) {
    int g = i >> 16, r = (i >> 8) & 255, n = i & 255;
    const float* W0 = (g == 0) ? Wqd : (g == 1) ? Wkd : Wvd;
    const float* W1 = (g == 0) ? Wqa : (g == 1) ? Wka : Wva;
    Wcat[i] = (n < 128) ? W0[r * 128 + n] : W1[r * 128 + (n - 128)];
  } else {
    int j = i - 3 * 256 * 256;
    if (j < 3 * 256) {
      int g = j >> 8, n = j & 255;
      const float* b0 = (g == 0) ? bqd : (g == 1) ? bkd : bvd;
      const float* b1 = (g == 0) ? bqa : (g == 1) ? bka : bva;
      bcat[j] = (n < 128) ? b0[n] : b1[n - 128];
    }
  }
}

// ---------------------------------------------------------------------------
// gemm256: Y[M x 256] = X[M x 256] @ W[256 x 256] + bias. 64x64 block tile,
// 4x4 micro-tile per thread, 16-wide K chunks staged in LDS.
// ---------------------------------------------------------------------------
__global__ __launch_bounds__(256) void gemm256_kernel(
    const float* __restrict__ X, const float* __restrict__ W,
    const float* __restrict__ bias, float* __restrict__ Y)
{
  __shared__ float As[16][68];
  __shared__ float Bs[16][68];
  const int t = threadIdx.x;
  const int m0 = blockIdx.x * 64;
  const int n0 = blockIdx.y * 64;
  const int tm = t >> 4, tn = t & 15;
  const int mA = t >> 2, kqA = t & 3;
  const int kB = t >> 4, nqB = t & 15;

  float acc[4][4];
#pragma unroll
  for (int i = 0; i < 4; ++i)
#pragma unroll
    for (int j = 0; j < 4; ++j) acc[i][j] = 0.f;

  for (int k0 = 0; k0 < 256; k0 += 16) {
    float4 a = *(const float4*)&X[(size_t)(m0 + mA) * 256 + k0 + 4 * kqA];
    float4 b = *(const float4*)&W[(size_t)(k0 + kB) * 256 + n0 + 4 * nqB];
    __syncthreads();
    As[4 * kqA + 0][mA] = a.x;
    As[4 * kqA + 1][mA] = a.y;
    As[4 * kqA + 2][mA] = a.z;
    As[4 * kqA + 3][mA] = a.w;
    *(float4*)&Bs[kB][4 * nqB] = b;
    __syncthreads();
#pragma unroll
    for (int kk = 0; kk < 16; ++kk) {
      float4 av = *(const float4*)&As[kk][4 * tm];
      float4 bv = *(const float4*)&Bs[kk][4 * tn];
      float ar[4] = {av.x, av.y, av.z, av.w};
      float br[4] = {bv.x, bv.y, bv.z, bv.w};
#pragma unroll
      for (int i = 0; i < 4; ++i)
#pragma unroll
        for (int j = 0; j < 4; ++j) acc[i][j] = fmaf(ar[i], br[j], acc[i][j]);
    }
  }
  float4 bv = *(const float4*)&bias[n0 + 4 * tn];
#pragma unroll
  for (int i = 0; i < 4; ++i) {
    float4 o;
    o.x = acc[i][0] + bv.x; o.y = acc[i][1] + bv.y;
    o.z = acc[i][2] + bv.z; o.w = acc[i][3] + bv.w;
    *(float4*)&Y[(size_t)(m0 + 4 * tm + i) * 256 + n0 + 4 * tn] = o;
  }
}

// ---------------------------------------------------------------------------
// dist_stats: per (b,q) row of dist+neg -> rowmax and 1/sum(exp)
// ---------------------------------------------------------------------------
__global__ __launch_bounds__(256) void dist_stats_kernel(
    const float* __restrict__ dist, const float* __restrict__ mask,
    float* __restrict__ dmax, float* __restrict__ dinv)
{
  const int t = threadIdx.x;
  const int w = t >> 6, lane = t & 63;
  const int row = blockIdx.x * 4 + w;
  const int b = row >> 10;
  const float* dr = dist + (size_t)row * 1024;
  const float* mr = mask + b * 1024;
  float v[16];
  float m = -3.0e38f;
#pragma unroll
  for (int j = 0; j < 16; ++j) {
    int c = lane + 64 * j;
    v[j] = dr[c] - 1e9f * mr[c];
    m = fmaxf(m, v[j]);
  }
#pragma unroll
  for (int off = 32; off >= 1; off >>= 1) m = fmaxf(m, __shfl_xor(m, off));
  float s = 0.f;
#pragma unroll
  for (int j = 0; j < 16; ++j) s += __expf(v[j] - m);
#pragma unroll
  for (int off = 32; off >= 1; off >>= 1) s += __shfl_xor(s, off);
  if (lane == 0) { dmax[row] = m; dinv[row] = 1.0f / s; }
}

// ---------------------------------------------------------------------------
// attn_fused: per block = (b, h, 16 q-rows). Phase 1: logits -> LDS (no VGPR
// spill). Softmax stats via own-lane reads + shuffle. Phase 2: reweight,
// write w, accumulate PV in registers. Epilogue: LDS transpose-reduce -> conc.
// Row-group = 32 contiguous lanes (wave-synchronous; no cross-lane LDS reads
// without a barrier).
// ---------------------------------------------------------------------------
__global__ __launch_bounds__(256) void attn_fused_kernel(
    const float* __restrict__ Qc, const float* __restrict__ Kc,
    const float* __restrict__ Vc, const float* __restrict__ mask,
    const float* __restrict__ adj, const float* __restrict__ dist,
    const float* __restrict__ dmax, const float* __restrict__ dinv,
    float* __restrict__ wout, float* __restrict__ conc)
{
  __shared__ float Ls[17408];      // phase1/2: logits|e as [16][1024]; epilogue: red[512][34]
  __shared__ float KVs[64][36];    // K-tile, then V-tile staging
  const int t = threadIdx.x;
  const int bid = blockIdx.x;
  const int qb = bid & 63, h = (bid >> 6) & 7, b = bid >> 9;
  const int q0 = qb * 16;
  const int branch = h >> 2;
  const int boff = branch * 128 + (h & 3) * 32;
  const int tp = t >> 5, tc = t & 31;
  const int r0 = 2 * tp;                 // local rows r0, r0+1
  const int gr0 = q0 + r0;

  // Q rows into registers (dead after phase 1; registers reused for o accum)
  const float* qrow0 = Qc + ((size_t)(b * 1024 + gr0)) * 256 + boff;
  const float* qrow1 = qrow0 + 256;
  float Q0[32], Q1[32];
#pragma unroll
  for (int dq = 0; dq < 8; ++dq) {
    float4 a = *(const float4*)&qrow0[4 * dq];
    Q0[4 * dq + 0] = a.x; Q0[4 * dq + 1] = a.y; Q0[4 * dq + 2] = a.z; Q0[4 * dq + 3] = a.w;
    float4 c = *(const float4*)&qrow1[4 * dq];
    Q1[4 * dq + 0] = c.x; Q1[4 * dq + 1] = c.y; Q1[4 * dq + 2] = c.z; Q1[4 * dq + 3] = c.w;
  }

  const float* kb = Kc + (size_t)(b * 1024) * 256 + boff;
  const float* mr = mask + b * 1024;
  const int sr = t >> 2, sq = t & 3;     // staging: row sr (0..63), dim-quads sq, sq+4

  // -------- Phase 1: logits -> LDS --------
  for (int cc = 0; cc < 16; ++cc) {
    const int c0 = cc * 64;
    float4 ka = *(const float4*)&kb[(size_t)(c0 + sr) * 256 + 4 * sq];
    float4 kc2 = *(const float4*)&kb[(size_t)(c0 + sr) * 256 + 16 + 4 * sq];
    __syncthreads();
    *(float4*)&KVs[sr][4 * sq] = ka;
    *(float4*)&KVs[sr][16 + 4 * sq] = kc2;
    __syncthreads();
#pragma unroll
    for (int j2 = 0; j2 < 2; ++j2) {
      const int cl = tc + 32 * j2, c = c0 + cl;
      float s0 = 0.f, s1 = 0.f;
#pragma unroll
      for (int dq = 0; dq < 8; ++dq) {
        float4 kv = *(const float4*)&KVs[cl][4 * dq];
        s0 = fmaf(Q0[4 * dq + 0], kv.x, s0);
        s0 = fmaf(Q0[4 * dq + 1], kv.y, s0);
        s0 = fmaf(Q0[4 * dq + 2], kv.z, s0);
        s0 = fmaf(Q0[4 * dq + 3], kv.w, s0);
        s1 = fmaf(Q1[4 * dq + 0], kv.x, s1);
        s1 = fmaf(Q1[4 * dq + 1], kv.y, s1);
        s1 = fmaf(Q1[4 * dq + 2], kv.z, s1);
        s1 = fmaf(Q1[4 * dq + 3], kv.w, s1);
      }
      float ng = -1e9f * mr[c];
      Ls[r0 * 1024 + c] = fmaf(s0, SCALE, ng);
      Ls[(r0 + 1) * 1024 + c] = fmaf(s1, SCALE, ng);
    }
  }
  __syncthreads();   // also blocks LDS store->load forwarding back into VGPRs

  // -------- Softmax stats (own-lane LDS reads + shuffle across 32-lane group)
  float m0v = -3.0e38f, m1v = -3.0e38f;
#pragma unroll
  for (int j = 0; j < 32; ++j) {
    int c = tc + 32 * j;
    m0v = fmaxf(m0v, Ls[r0 * 1024 + c]);
    m1v = fmaxf(m1v, Ls[(r0 + 1) * 1024 + c]);
  }
#pragma unroll
  for (int off = 16; off >= 1; off >>= 1) {
    m0v = fmaxf(m0v, __shfl_xor(m0v, off));
    m1v = fmaxf(m1v, __shfl_xor(m1v, off));
  }
  float s0v = 0.f, s1v = 0.f;
#pragma unroll
  for (int j = 0; j < 32; ++j) {
    int c = tc + 32 * j;
    float e0 = __expf(Ls[r0 * 1024 + c] - m0v);
    float e1 = __expf(Ls[(r0 + 1) * 1024 + c] - m1v);
    Ls[r0 * 1024 + c] = e0;
    Ls[(r0 + 1) * 1024 + c] = e1;
    s0v += e0; s1v += e1;
  }
#pragma unroll
  for (int off = 16; off >= 1; off >>= 1) {
    s0v += __shfl_xor(s0v, off);
    s1v += __shfl_xor(s1v, off);
  }
  const float inv0 = 1.0f / s0v, inv1 = 1.0f / s1v;

  // -------- Phase 2: reweight + w write + PV accumulate --------
  float o0[32], o1[32];
#pragma unroll
  for (int d = 0; d < 32; ++d) { o0[d] = 0.f; o1[d] = 0.f; }

  float dm0 = 0.f, di0 = 0.f, dm1 = 0.f, di1 = 0.f;
  const float *dr0 = nullptr, *dr1 = nullptr, *ar0 = nullptr, *ar1 = nullptr;
  if (branch == 0) {
    dm0 = dmax[b * 1024 + gr0];     di0 = dinv[b * 1024 + gr0];
    dm1 = dmax[b * 1024 + gr0 + 1]; di1 = dinv[b * 1024 + gr0 + 1];
    dr0 = dist + (size_t)(b * 1024 + gr0) * 1024;
    dr1 = dr0 + 1024;
  } else {
    ar0 = adj + (size_t)(b * 1024 + gr0) * 1024;
    ar1 = ar0 + 1024;
  }
  const float* vb = Vc + (size_t)(b * 1024) * 256 + boff;
  const size_t wrow0 = ((size_t)(b * 8 + h) * 1024 + gr0) * 1024;
  const size_t wrow1 = wrow0 + 1024;

  for (int cc = 0; cc < 16; ++cc) {
    const int c0 = cc * 64;
    float4 va = *(const float4*)&vb[(size_t)(c0 + sr) * 256 + 4 * sq];
    float4 vc2 = *(const float4*)&vb[(size_t)(c0 + sr) * 256 + 16 + 4 * sq];
    __syncthreads();
    *(float4*)&KVs[sr][4 * sq] = va;
    *(float4*)&KVs[sr][16 + 4 * sq] = vc2;
    __syncthreads();
#pragma unroll
    for (int j2 = 0; j2 < 2; ++j2) {
      const int cl = tc + 32 * j2, c = c0 + cl;
      float e0 = Ls[r0 * 1024 + c] * inv0;
      float e1 = Ls[(r0 + 1) * 1024 + c] * inv1;
      float f0, f1;
      if (branch == 0) {
        float ng = -1e9f * mr[c];
        f0 = __expf(dr0[c] + ng - dm0) * di0;
        f1 = __expf(dr1[c] + ng - dm1) * di1;
      } else {
        f0 = ar0[c];
        f1 = ar1[c];
      }
      float w0 = e0 * f0, w1 = e1 * f1;
      wout[wrow0 + c] = w0;
      wout[wrow1 + c] = w1;
#pragma unroll
      for (int dq = 0; dq < 8; ++dq) {
        float4 vv = *(const float4*)&KVs[cl][4 * dq];
        o0[4 * dq + 0] = fmaf(w0, vv.x, o0[4 * dq + 0]);
        o0[4 * dq + 1] = fmaf(w0, vv.y, o0[4 * dq + 1]);
        o0[4 * dq + 2] = fmaf(w0, vv.z, o0[4 * dq + 2]);
        o0[4 * dq + 3] = fmaf(w0, vv.w, o0[4 * dq + 3]);
        o1[4 * dq + 0] = fmaf(w1, vv.x, o1[4 * dq + 0]);
        o1[4 * dq + 1] = fmaf(w1, vv.y, o1[4 * dq + 1]);
        o1[4 * dq + 2] = fmaf(w1, vv.z, o1[4 * dq + 2]);
        o1[4 * dq + 3] = fmaf(w1, vv.w, o1[4 * dq + 3]);
      }
    }
  }

  // -------- Epilogue: transpose-reduce o across the 32-lane col groups ------
  __syncthreads();                        // done reading Ls as e-values
  {
    const int slot0 = (r0 * 32 + tc) * 34;
    const int slot1 = ((r0 + 1) * 32 + tc) * 34;
#pragma unroll
    for (int d2 = 0; d2 < 16; ++d2) {
      float2 u; u.x = o0[2 * d2]; u.y = o0[2 * d2 + 1];
      *(float2*)&Ls[slot0 + 2 * d2] = u;
      float2 v; v.x = o1[2 * d2]; v.y = o1[2 * d2 + 1];
      *(float2*)&Ls[slot1 + 2 * d2] = v;
    }
  }
  __syncthreads();
  {
    const int rr = t >> 4, dd = t & 15;   // row rr, dim pair 2dd..2dd+1
    float a0 = 0.f, a1 = 0.f;
#pragma unroll
    for (int tcx = 0; tcx < 32; ++tcx) {
      float2 v = *(const float2*)&Ls[(rr * 32 + tcx) * 34 + 2 * dd];
      a0 += v.x; a1 += v.y;
    }
    float2 o; o.x = a0; o.y = a1;
    *(float2*)&conc[((size_t)(b * 1024) + q0 + rr) * 256 + boff + 2 * dd] = o;
  }
}

// ---------------------------------------------------------------------------
extern "C" void kernel_launch(void* const* d_in, const int* in_sizes, int n_in,
                              void* d_out, int out_size, void* d_ws, size_t ws_size,
                              hipStream_t stream)
{
  const float* v_ori = (const float*)d_in[0];
  const float* k_ori = (const float*)d_in[1];
  const float* q_ori = (const float*)d_in[2];
  const float* mask  = (const float*)d_in[3];
  const float* adj   = (const float*)d_in[4];
  const float* dist  = (const float*)d_in[5];
  const float* Wqd = (const float*)d_in[6];  const float* bqd = (const float*)d_in[7];
  const float* Wkd = (const float*)d_in[8];  const float* bkd = (const float*)d_in[9];
  const float* Wvd = (const float*)d_in[10]; const float* bvd = (const float*)d_in[11];
  const float* Wqa = (const float*)d_in[12]; const float* bqa = (const float*)d_in[13];
  const float* Wka = (const float*)d_in[14]; const float* bka = (const float*)d_in[15];
  const float* Wva = (const float*)d_in[16]; const float* bva = (const float*)d_in[17];
  const float* Wo  = (const float*)d_in[18]; const float* bo  = (const float*)d_in[19];

  float* out = (float*)d_out;
  float* ws  = (float*)d_ws;
  float* Qc    = ws;                  // 16384*256
  float* Kc    = Qc + 4194304;
  float* Vc    = Kc + 4194304;
  float* conc  = Vc + 4194304;        // 16384*256
  float* dmaxb = conc + 4194304;      // 16384
  float* dinvb = dmaxb + 16384;       // 16384
  float* Wcat  = dinvb + 16384;       // 3*65536
  float* bcat  = Wcat + 196608;       // 3*256

  pack_kernel<<<771, 256, 0, stream>>>(Wqd, Wqa, Wkd, Wka, Wvd, Wva,
                                       bqd, bqa, bkd, bka, bvd, bva, Wcat, bcat);
  dim3 gg(256, 4);
  gemm256_kernel<<<gg, 256, 0, stream>>>(q_ori, Wcat,          bcat,       Qc);
  gemm256_kernel<<<gg, 256, 0, stream>>>(k_ori, Wcat + 65536,  bcat + 256, Kc);
  gemm256_kernel<<<gg, 256, 0, stream>>>(v_ori, Wcat + 131072, bcat + 512, Vc);
  dist_stats_kernel<<<4096, 256, 0, stream>>>(dist, mask, dmaxb, dinvb);
  attn_fused_kernel<<<8192, 256, 0, stream>>>(Qc, Kc, Vc, mask, adj, dist,
                                              dmaxb, dinvb, out + OUTW, conc);
  gemm256_kernel<<<gg, 256, 0, stream>>>(conc, Wo, bo, out);
}